// Round 4
// baseline (4071.310 us; speedup 1.0000x reference)
//
#include <hip/hip_runtime.h>
#include <hip/hip_bf16.h>
#include <math.h>

#define BB 256
#define LL 256
#define DD 4
#define HH 1024
#define SS 100
#define OUTD 3
#define X0 768          /* L*OUT */
#define K1 1792         /* 768 + 1024 */
#define K2 2048
#define NG 4096
#define BKB 128

typedef __attribute__((ext_vector_type(4))) float f32x4;
typedef __attribute__((ext_vector_type(8))) short bf16x8;
typedef __hip_bfloat16 bf16;

__device__ __forceinline__ float sigmoidf_(float x){ return 1.0f/(1.0f + __expf(-x)); }

__device__ __forceinline__ void gll16(const void* g, void* l){
  __builtin_amdgcn_global_load_lds((const __attribute__((address_space(1))) unsigned int*)g,
                                   (__attribute__((address_space(3))) unsigned int*)l, 16, 0, 0);
}

// =====================================================================
// cell_v4b: plain GEMM 256x4096xK with interleaved W rows (n' = col*4+gate)
// + fused LSTM epilogue.
// Grid: 256 blocks = 4 m-tiles x 64 n-tiles (XCD-grouped by n).
// Block: 256 thr = 4 waves = (2 m-halves) x (2 K-halves, in-block split-K).
// W tile: 64 rows x 256B/stage = 16 chunks of 1KB; wave wm stages chunks
// c = wm*8 + j (rows wm*32..wm*32+31)  [r3 bug: both waves staged rows 0..31].
// A loaded DIRECT global->reg (L2 broadcast, reuse-1).
// =====================================================================
template<int K, int KH, bool WTANH>
__global__ __launch_bounds__(256, 1) void cell_v4(
    const bf16* __restrict__ Acat,   // [256][K]
    const bf16* __restrict__ Wr,     // [4096][K], rows interleaved col*4+gate
    const float* __restrict__ biasr, // [4096] interleaved
    float* __restrict__ cst,
    bf16* __restrict__ dstA, int ldA, bf16* __restrict__ dstB, int ldB)
{
  constexpr int NT = KH / 128;
  __shared__ __align__(16) char smem[81920]; // W: [wk][buf][64 rows][256B] = 64KB; gbuf f32 16KB @65536

  const int tid  = threadIdx.x;
  const int wave = tid >> 6, lane = tid & 63;
  const int wm = wave & 1, wk = wave >> 1;
  const int lr = lane & 15, kq16 = lane >> 4;

  // block -> (m_tile, n_tile), XCD-grouped: xcd owns n-tiles [8x, 8x+8)
  const int bid = blockIdx.x;
  const int xcd = bid & 7, within = bid >> 3;
  const int ntile = xcd * 8 + (within & 7);
  const int mtile = within >> 3;            // 0..3
  const int m0 = mtile * 64;
  const int n0 = ntile * 64;                // n' base

  // ---- W staging: wave wm stages chunks c = wm*8+j (rows c*4 + lane>>4) ----
  // linear LDS dest (chunk c at c*1024, lane covers +lane*16);
  // swizzle: LDS[row][slot] = G[row][slot ^ (row&7)]
  const char* srcW[8];
  int ldsoff[8];
  #pragma unroll
  for (int j = 0; j < 8; j++){
    int c = wm*8 + j;
    int row = c*4 + (lane >> 4);
    int slot = (lane & 15) ^ (row & 7);
    srcW[j] = (const char*)(Wr + (size_t)(n0 + row) * K + wk * KH) + slot * 16;
    ldsoff[j] = c * 1024;
  }

  // ---- A direct-load base pointers (per m-frag) ----
  const char* aptr[2];
  #pragma unroll
  for (int mt = 0; mt < 2; mt++)
    aptr[mt] = (const char*)(Acat + (size_t)(m0 + wm*32 + mt*16 + lr) * K + wk * KH) + kq16 * 16;

  // ---- W fragment read offsets within a buffer ----
  int woff[4][4];
  #pragma unroll
  for (int nt = 0; nt < 4; nt++)
    #pragma unroll
    for (int s = 0; s < 4; s++){
      int row = nt*16 + lr;
      woff[nt][s] = row*256 + (((s*4 + kq16) ^ (row & 7)) << 4);
    }

  f32x4 acc[2][4] = {};
  bf16x8 Aa[2][4], Ab[2][4];

  // ---- prologue: stage 0 ----
  {
    char* db = smem + wk*32768;
    #pragma unroll
    for (int j = 0; j < 8; j++) gll16(srcW[j], db + ldsoff[j]);
    __builtin_amdgcn_sched_barrier(0);
    #pragma unroll
    for (int mt = 0; mt < 2; mt++)
      #pragma unroll
      for (int s = 0; s < 4; s++)
        Aa[mt][s] = *(const bf16x8*)(aptr[mt] + s*64);
  }

#define CELL_BODY(I, CUR, NXT, LAST)                                          \
  {                                                                           \
    __builtin_amdgcn_s_barrier();                                             \
    if (!(LAST)) {                                                            \
      char* db = smem + wk*32768 + (((I)+1)&1)*16384;                         \
      _Pragma("unroll")                                                       \
      for (int j = 0; j < 8; j++)                                             \
        gll16(srcW[j] + (size_t)((I)+1)*256, db + ldsoff[j]);                 \
      __builtin_amdgcn_sched_barrier(0);                                      \
      _Pragma("unroll")                                                       \
      for (int mt = 0; mt < 2; mt++)                                          \
        _Pragma("unroll")                                                     \
        for (int s = 0; s < 4; s++)                                           \
          NXT[mt][s] = *(const bf16x8*)(aptr[mt] + (size_t)((I)+1)*256 + s*64);\
      asm volatile("s_waitcnt vmcnt(16)" ::: "memory");                       \
    } else {                                                                  \
      asm volatile("s_waitcnt vmcnt(0)" ::: "memory");                        \
    }                                                                         \
    __builtin_amdgcn_s_barrier();                                             \
    __builtin_amdgcn_sched_barrier(0);                                        \
    const char* wb = smem + wk*32768 + ((I)&1)*16384;                         \
    bf16x8 Wf[4][4];                                                          \
    _Pragma("unroll")                                                         \
    for (int nt = 0; nt < 4; nt++)                                            \
      _Pragma("unroll")                                                       \
      for (int s = 0; s < 4; s++)                                             \
        Wf[nt][s] = *(const bf16x8*)(wb + woff[nt][s]);                       \
    _Pragma("unroll")                                                         \
    for (int s = 0; s < 4; s++)                                               \
      _Pragma("unroll")                                                       \
      for (int mt = 0; mt < 2; mt++)                                          \
        _Pragma("unroll")                                                     \
        for (int nt = 0; nt < 4; nt++)                                        \
          acc[mt][nt] = __builtin_amdgcn_mfma_f32_16x16x32_bf16(              \
              CUR[mt][s], Wf[nt][s], acc[mt][nt], 0,0,0);                     \
    __builtin_amdgcn_sched_barrier(0);                                        \
  }

  {
    int i = 0;
    for (; i + 2 <= NT; i += 2){
      CELL_BODY(i,   Aa, Ab, false);
      CELL_BODY(i+1, Ab, Aa, ((i+2==NT) && !(NT & 1)));
    }
    if (NT & 1) CELL_BODY(NT-1, Aa, Ab, true);
  }
#undef CELL_BODY

  // ---- in-block split-K reduction + fused LSTM pointwise ----
  float* gbuf = (float*)(smem + 65536);     // [64][64] f32
  const int rq = lane >> 4, cr = lane & 15;
  __syncthreads();
  if (wk == 0){
    #pragma unroll
    for (int mt = 0; mt < 2; mt++)
      #pragma unroll
      for (int nt = 0; nt < 4; nt++)
        #pragma unroll
        for (int j = 0; j < 4; j++)
          gbuf[(wm*32 + mt*16 + rq*4 + j)*64 + nt*16 + cr] = acc[mt][nt][j];
  }
  __syncthreads();
  if (wk == 1){
    #pragma unroll
    for (int mt = 0; mt < 2; mt++)
      #pragma unroll
      for (int nt = 0; nt < 4; nt++)
        #pragma unroll
        for (int j = 0; j < 4; j++)
          gbuf[(wm*32 + mt*16 + rq*4 + j)*64 + nt*16 + cr] += acc[mt][nt][j];
  }
  __syncthreads();

  #pragma unroll
  for (int e = 0; e < 4; e++){
    int idx = e*256 + tid;                  // 64 rows x 16 cols
    int r = idx >> 4, cl = idx & 15;
    f32x4 g  = *(const f32x4*)&gbuf[r*64 + cl*4];
    f32x4 bi = *(const f32x4*)&biasr[n0 + cl*4];
    int m = m0 + r;
    int col = ntile*16 + cl;
    float gi = g[0] + bi[0];
    float gf = g[1] + bi[1];
    float gg = g[2] + bi[2];
    float go = g[3] + bi[3];
    float cold = cst[m*HH + col];
    float cn = sigmoidf_(gf)*cold + sigmoidf_(gi)*tanhf(gg);
    float hn = sigmoidf_(go)*tanhf(cn);
    cst[m*HH + col] = cn;
    dstA[(size_t)m*ldA + col] = __float2bfloat16(hn);
    dstB[(size_t)m*ldB + col] = __float2bfloat16(WTANH ? tanhf(hn) : hn);
  }
}

// =====================================================================
// dec v2 (unchanged): 64x64 tile, grid (4,12), 512 thr, K=1024.
// =====================================================================
__global__ __launch_bounds__(512) void dec_v2(
    const bf16* __restrict__ th, const bf16* __restrict__ Wl,
    const float* __restrict__ alphas, const float* __restrict__ betas,
    const float* __restrict__ baralphas, const float* __restrict__ snoise,
    float* __restrict__ prev, float* __restrict__ out,
    bf16* __restrict__ xnext, int t)
{
  __shared__ __align__(16) char smem[32768];
  const int tid  = threadIdx.x;
  const int wave = tid >> 6, lane = tid & 63;
  const int m0 = blockIdx.x * 64;
  const int n0 = blockIdx.y * 64;
  const int wm = wave >> 2, wn = wave & 3;
  const int l7 = lane & 7, l3 = lane >> 3;
  const int swz = 16 * (l7 ^ l3);

  const char* src[2];
  char* dstL[2][2];
  #pragma unroll
  for (int i = 0; i < 2; i++){
    int c = wave*2 + i;
    const bf16* base; size_t roff; int ldsoff;
    if (c < 8){ int row = c*8 + l3; base = th; roff = (size_t)(m0 + row)*HH; ldsoff = c*1024; }
    else { int wr = (c-8)*8 + l3;  base = Wl; roff = (size_t)(n0 + wr)*HH; ldsoff = 8192 + (c-8)*1024; }
    src[i] = (const char*)(base + roff) + swz;
    dstL[0][i] = smem + ldsoff;
    dstL[1][i] = smem + 16384 + ldsoff;
  }

  const int lr = lane & 15, kq = lane >> 4;
  const int rsw = (lr & 7) << 4;
  int offA[2][2], offB[2];
  #pragma unroll
  for (int mt = 0; mt < 2; mt++)
    #pragma unroll
    for (int s = 0; s < 2; s++){
      int row = wm*32 + mt*16 + lr;
      offA[mt][s] = row*BKB + ((s*64 + kq*16) ^ rsw);
    }
  #pragma unroll
  for (int s = 0; s < 2; s++){
    int wr = wn*16 + lr;
    offB[s] = 8192 + wr*BKB + ((s*64 + kq*16) ^ rsw);
  }

  f32x4 acc[2] = {};
  constexpr int NT = HH / 64;
  #pragma unroll
  for (int i = 0; i < 2; i++) gll16(src[i], dstL[0][i]);

  for (int tt = 0; tt < NT; ++tt){
    const int b = tt & 1;
    if (tt + 1 < NT){
      #pragma unroll
      for (int i = 0; i < 2; i++) gll16(src[i] + (size_t)(tt+1)*BKB, dstL[(tt+1)&1][i]);
      asm volatile("s_waitcnt vmcnt(2)" ::: "memory");
    } else {
      asm volatile("s_waitcnt vmcnt(0)" ::: "memory");
    }
    __builtin_amdgcn_s_barrier();
    __builtin_amdgcn_sched_barrier(0);

    const char* cbase = smem + b*16384;
    bf16x8 Af[2][2], Bf[2];
    #pragma unroll
    for (int mt = 0; mt < 2; mt++)
      #pragma unroll
      for (int s = 0; s < 2; s++) Af[mt][s] = *(const bf16x8*)(cbase + offA[mt][s]);
    #pragma unroll
    for (int s = 0; s < 2; s++) Bf[s] = *(const bf16x8*)(cbase + offB[s]);
    #pragma unroll
    for (int s = 0; s < 2; s++)
      #pragma unroll
      for (int mt = 0; mt < 2; mt++)
        acc[mt] = __builtin_amdgcn_mfma_f32_16x16x32_bf16(Af[mt][s], Bf[s], acc[mt], 0,0,0);

    __builtin_amdgcn_sched_barrier(0);
    __builtin_amdgcn_s_barrier();
  }

  const int idxs = SS - t;
  float a = alphas[idxs], ba = baralphas[idxs], be = betas[idxs];
  float coef = (1.0f - a) / sqrtf(1.0f - ba);
  float isq  = 1.0f / sqrtf(a);
  float nf = (t+1 < SS) ? sqrtf(be) : 0.0f;
  float* outp = out + (size_t)(SS-1-t) * (BB*X0);
  const int cr = lane & 15, rq = lane >> 4;
  #pragma unroll
  for (int mt = 0; mt < 2; mt++)
    #pragma unroll
    for (int j = 0; j < 4; j++){
      int m = m0 + wm*32 + mt*16 + rq*4 + j;
      int n = n0 + wn*16 + cr;
      float d = acc[mt][j];
      float p = prev[m*X0 + n];
      float dec = (p - coef*d)*isq + nf*snoise[t*BB + m];
      outp[m*X0 + n] = dec;
      prev[m*X0 + n] = dec;
      xnext[(size_t)m*K1 + n] = __float2bfloat16(dec);
    }
}

// =====================================================================
// setup-phase helpers
// =====================================================================
__device__ __forceinline__ void gemm32x32(const bf16* __restrict__ A, int lda,
                                          const bf16* __restrict__ W, int ldw,
                                          int m0, int wr0, int K,
                                          f32x4 acc[2][2], int lane)
{
  int r  = lane & 15;
  int kq = lane >> 4;
  const bf16* a0 = A + (size_t)(m0 + r)      * lda + kq*8;
  const bf16* a1 = A + (size_t)(m0 + 16 + r) * lda + kq*8;
  const bf16* b0 = W + (size_t)(wr0 + r)      * ldw + kq*8;
  const bf16* b1 = W + (size_t)(wr0 + 16 + r) * ldw + kq*8;
  for (int kk = 0; kk < K; kk += 32) {
    bf16x8 av0 = *(const bf16x8*)(a0 + kk);
    bf16x8 av1 = *(const bf16x8*)(a1 + kk);
    bf16x8 bv0 = *(const bf16x8*)(b0 + kk);
    bf16x8 bv1 = *(const bf16x8*)(b1 + kk);
    acc[0][0] = __builtin_amdgcn_mfma_f32_16x16x32_bf16(av0, bv0, acc[0][0], 0,0,0);
    acc[0][1] = __builtin_amdgcn_mfma_f32_16x16x32_bf16(av0, bv1, acc[0][1], 0,0,0);
    acc[1][0] = __builtin_amdgcn_mfma_f32_16x16x32_bf16(av1, bv0, acc[1][0], 0,0,0);
    acc[1][1] = __builtin_amdgcn_mfma_f32_16x16x32_bf16(av1, bv1, acc[1][1], 0,0,0);
  }
}

template<int EPI>
__global__ __launch_bounds__(256) void rgemm_kernel(
    const bf16* __restrict__ A, const bf16* __restrict__ W,
    const float* __restrict__ bias, const float* __restrict__ resid,
    bf16* __restrict__ d1, int ld1, bf16* __restrict__ d2, int ld2,
    float* __restrict__ f1, float* __restrict__ f2)
{
  int tid=threadIdx.x, wave=tid>>6, lane=tid&63;
  int m0 = blockIdx.x*32;
  int n0 = (blockIdx.y*4+wave)*32;
  f32x4 acc[2][2] = {};
  gemm32x32(A, HH, W, HH, m0, n0, HH, acc, lane);
  int cr=lane&15, rq=lane>>4;
  for (int r=0;r<2;r++) for (int c=0;c<2;c++) for (int j=0;j<4;j++) {
    int m = m0 + r*16+rq*4+j, n = n0 + c*16+cr;
    float v = acc[r][c][j] + bias[n];
    if (EPI==0) {
      float h = fmaxf(v,0.f) + resid[m*HH+n];
      d1[(size_t)m*ld1+n] = __float2bfloat16(h);
    } else if (EPI==1) {
      float tv = tanhf(v);
      if (n < HH) d1[(size_t)m*ld1+n] = __float2bfloat16(tv);
      else        d2[(size_t)m*ld2 + (n-HH)] = __float2bfloat16(tv);
    } else {
      float tv = tanhf(v);
      if (n < HH) f1[m*HH+n] = tv;
      else        f2[m*HH + (n-HH)] = tv;
    }
  }
}

// W rows interleaved: n' = col*4 + gate
__global__ void prep_w0_kernel(const float* __restrict__ Wih0, const float* __restrict__ Whh0,
                               bf16* __restrict__ W0r){
  int i = blockIdx.x*256 + threadIdx.x;
  if (i >= NG*K1) return;
  int np = i / K1, k = i % K1;
  int col = np >> 2, g = np & 3;
  int srow = g*HH + col;
  float v = (k < X0) ? Wih0[srow*X0 + k] : Whh0[srow*HH + (k - X0)];
  W0r[i] = __float2bfloat16(v);
}
__global__ void prep_w1_kernel(const float* __restrict__ Wih1, const float* __restrict__ Whh1,
                               bf16* __restrict__ W1r){
  int i = blockIdx.x*256 + threadIdx.x;
  if (i >= NG*K2) return;
  int np = i / K2, k = i % K2;
  int col = np >> 2, g = np & 3;
  int srow = g*HH + col;
  float v = (k < HH) ? Wih1[srow*HH + k] : Whh1[srow*HH + (k - HH)];
  W1r[i] = __float2bfloat16(v);
}
__global__ void cvt_kernel(const float* __restrict__ s, bf16* __restrict__ d, int n){
  int i = blockIdx.x*256 + threadIdx.x;
  if (i < n) d[i] = __float2bfloat16(s[i]);
}
__global__ void prep_bias_kernel(const float* bih0, const float* bhh0,
                                 const float* bih1, const float* bhh1,
                                 float* b0, float* b1){
  int i = blockIdx.x*256 + threadIdx.x;
  if (i < NG){
    int col = i >> 2, g = i & 3;
    int s = g*HH + col;
    b0[i] = bih0[s] + bhh0[s];
    b1[i] = bih1[s] + bhh1[s];
  }
}
__global__ void init_x_kernel(const float* __restrict__ z, float* __restrict__ prev,
                              bf16* __restrict__ xcat1, float* __restrict__ out){
  int i = blockIdx.x*256 + threadIdx.x;
  if (i >= BB*X0) return;
  int m = i / X0, col = i % X0;
  int l = col / OUTD, d = col % OUTD;
  float v = z[(size_t)(m*LL + l)*DD + d];
  prev[i] = v;
  out[(size_t)(SS-1)*BB*X0 + i] = v;
  xcat1[(size_t)m*K1 + col] = __float2bfloat16(v);
}
__global__ void r1_kernel(const float* __restrict__ n0,
    const float* __restrict__ A1a, const float* __restrict__ b1a,
    const float* __restrict__ A1b, const float* __restrict__ b1b,
    float* __restrict__ h1fa, bf16* __restrict__ h1ba,
    float* __restrict__ h1fb, bf16* __restrict__ h1bb){
  int gid = blockIdx.x*256 + threadIdx.x;
  if (gid >= BB*2*HH) return;
  int m = gid >> 11;
  int col = gid & 2047;
  const float* A1; const float* b1; float* hf; bf16* hb; int c;
  if (col < HH){ A1=A1a; b1=b1a; hf=h1fa; hb=h1ba; c=col; }
  else         { A1=A1b; b1=b1b; hf=h1fb; hb=h1bb; c=col-HH; }
  float v = b1[c];
  for (int d=0; d<DD; d++) v += n0[m*DD + d] * A1[c*DD + d];
  v = fmaxf(v, 0.f);
  hf[m*HH + c] = v;
  hb[m*HH + c] = __float2bfloat16(v);
}

static inline size_t alup(size_t x){ return (x + 255) & ~(size_t)255; }

extern "C" void kernel_launch(void* const* d_in, const int* in_sizes, int n_in,
                              void* d_out, int out_size, void* d_ws, size_t ws_size,
                              hipStream_t stream) {
  const float* z      = (const float*)d_in[4];
  const float* n0     = (const float*)d_in[5];
  const float* snoise = (const float*)d_in[6];
  const float* alphas = (const float*)d_in[7];
  const float* betas  = (const float*)d_in[8];
  const float* barals = (const float*)d_in[9];
  const float* A1a = (const float*)d_in[10]; const float* b1a = (const float*)d_in[11];
  const float* A2a = (const float*)d_in[12]; const float* b2a = (const float*)d_in[13];
  const float* A3a = (const float*)d_in[14]; const float* b3a = (const float*)d_in[15];
  const float* A1b = (const float*)d_in[16]; const float* b1b = (const float*)d_in[17];
  const float* A2b = (const float*)d_in[18]; const float* b2b = (const float*)d_in[19];
  const float* A3b = (const float*)d_in[20]; const float* b3b = (const float*)d_in[21];
  const float* Wih0 = (const float*)d_in[22]; const float* Whh0 = (const float*)d_in[23];
  const float* bih0 = (const float*)d_in[24]; const float* bhh0 = (const float*)d_in[25];
  const float* Wih1 = (const float*)d_in[26]; const float* Whh1 = (const float*)d_in[27];
  const float* bih1 = (const float*)d_in[28]; const float* bhh1 = (const float*)d_in[29];
  const float* Wlin = (const float*)d_in[30];
  float* out = (float*)d_out;

  char* p = (char*)d_ws;
  size_t off = 0;
  auto take = [&](size_t bytes)->char*{ char* r = p + off; off = alup(off + bytes); return r; };
  bf16* W0cat = (bf16*)take((size_t)NG*K1*2);
  bf16* W1cat = (bf16*)take((size_t)NG*K2*2);
  bf16* WlinB = (bf16*)take((size_t)X0*HH*2);
  bf16* A2aB  = (bf16*)take((size_t)HH*HH*2);
  bf16* A2bB  = (bf16*)take((size_t)HH*HH*2);
  bf16* A3aB  = (bf16*)take((size_t)2*HH*HH*2);
  bf16* A3bB  = (bf16*)take((size_t)2*HH*HH*2);
  float* bias0 = (float*)take(NG*4);
  float* bias1 = (float*)take(NG*4);
  bf16* xcat0 = (bf16*)take((size_t)BB*K1*2);
  bf16* xcat1 = (bf16*)take((size_t)BB*K1*2);
  bf16* x2_0  = (bf16*)take((size_t)BB*K2*2);
  bf16* x2_1  = (bf16*)take((size_t)BB*K2*2);
  bf16* th    = (bf16*)take((size_t)BB*HH*2);
  float* c0   = (float*)take((size_t)BB*HH*4);
  float* c1   = (float*)take((size_t)BB*HH*4);
  float* prev = (float*)take((size_t)BB*X0*4);
  float* h1fa = (float*)take((size_t)BB*HH*4);
  float* h1fb = (float*)take((size_t)BB*HH*4);
  bf16* h1ba  = (bf16*)take((size_t)BB*HH*2);
  bf16* h1bb  = (bf16*)take((size_t)BB*HH*2);
  bf16* h2ba  = (bf16*)take((size_t)BB*HH*2);
  bf16* h2bb  = (bf16*)take((size_t)BB*HH*2);
  (void)ws_size; (void)in_sizes; (void)n_in; (void)out_size;

  prep_w0_kernel<<<(NG*K1+255)/256, 256, 0, stream>>>(Wih0, Whh0, W0cat);
  prep_w1_kernel<<<(NG*K2+255)/256, 256, 0, stream>>>(Wih1, Whh1, W1cat);
  cvt_kernel<<<(X0*HH+255)/256, 256, 0, stream>>>(Wlin, WlinB, X0*HH);
  cvt_kernel<<<(HH*HH+255)/256, 256, 0, stream>>>(A2a, A2aB, HH*HH);
  cvt_kernel<<<(HH*HH+255)/256, 256, 0, stream>>>(A2b, A2bB, HH*HH);
  cvt_kernel<<<(2*HH*HH+255)/256, 256, 0, stream>>>(A3a, A3aB, 2*HH*HH);
  cvt_kernel<<<(2*HH*HH+255)/256, 256, 0, stream>>>(A3b, A3bB, 2*HH*HH);
  prep_bias_kernel<<<(NG+255)/256, 256, 0, stream>>>(bih0, bhh0, bih1, bhh1, bias0, bias1);
  init_x_kernel<<<(BB*X0+255)/256, 256, 0, stream>>>(z, prev, xcat1, out);
  r1_kernel<<<(BB*2*HH+255)/256, 256, 0, stream>>>(n0, A1a, b1a, A1b, b1b, h1fa, h1ba, h1fb, h1bb);
  rgemm_kernel<0><<<dim3(8,8), 256, 0, stream>>>(h1ba, A2aB, b2a, h1fa, h2ba, HH, nullptr, 0, nullptr, nullptr);
  rgemm_kernel<0><<<dim3(8,8), 256, 0, stream>>>(h1bb, A2bB, b2b, h1fb, h2bb, HH, nullptr, 0, nullptr, nullptr);
  rgemm_kernel<1><<<dim3(8,16), 256, 0, stream>>>(h2ba, A3aB, b3a, nullptr, xcat1 + X0, K1, x2_1 + HH, K2, nullptr, nullptr);
  rgemm_kernel<2><<<dim3(8,16), 256, 0, stream>>>(h2bb, A3bB, b3b, nullptr, nullptr, 0, nullptr, 0, c0, c1);

  for (int t = 1; t < SS; t++) {
    bf16* xc  = (t & 1) ? xcat1 : xcat0;
    bf16* xn  = (t & 1) ? xcat0 : xcat1;
    bf16* x2c = (t & 1) ? x2_1 : x2_0;
    bf16* x2n = (t & 1) ? x2_0 : x2_1;
    cell_v4<K1, 896, false><<<256, 256, 0, stream>>>(
        xc, W0cat, bias0, c0, x2c, K2, xn + X0, K1);
    cell_v4<K2, 1024, true><<<256, 256, 0, stream>>>(
        x2c, W1cat, bias1, c1, x2n + HH, K2, th, HH);
    dec_v2<<<dim3(4,12), 512, 0, stream>>>(
        th, WlinB, alphas, betas, barals, snoise, prev, out, xn, t);
  }
}